// Round 4
// baseline (1006.534 us; speedup 1.0000x reference)
//
#include <hip/hip_runtime.h>
#include <hip/hip_bf16.h>

typedef _Float16 f16x8 __attribute__((ext_vector_type(8)));
typedef float f32x4 __attribute__((ext_vector_type(4)));

#define H 128
#define FEAT 7
#define ROWS 64

__device__ __forceinline__ float conv3(float x, float w, float b) {
    x = fmaxf(fmaf(w, x, b), 0.f);
    x = fmaxf(fmaf(w, x, b), 0.f);
    x = fmaxf(fmaf(w, x, b), 0.f);
    return x;
}
__device__ __forceinline__ float sigm(float x) { return 1.f / (1.f + __expf(-x)); }

// Pack fp32 row-major W[k][n] -> f16 MFMA-B-fragment layout: P[((k>>3)*N + n)*8 + (k&7)]
__global__ __launch_bounds__(256) void pack_weights(
    const float* __restrict__ Wr, const float* __restrict__ Wh, const float* __restrict__ Wz,
    _Float16* __restrict__ Pr, _Float16* __restrict__ Ph, _Float16* __restrict__ Pz)
{
    int idx = blockIdx.x * 256 + threadIdx.x;
    if (idx < 384 * 384) {
        int k = idx / 384, n = idx % 384;
        Pr[((size_t)(k >> 3) * 384 + n) * 8 + (k & 7)] = (_Float16)Wr[idx];
    }
    if (idx < 384 * 128) {
        int k = idx / 128, n = idx % 128;
        Ph[((size_t)(k >> 3) * 128 + n) * 8 + (k & 7)] = (_Float16)Wh[idx];
    }
    if (idx < 512 * 512) {
        int k = idx / 512, n = idx % 512;
        Pz[((size_t)(k >> 3) * 512 + n) * 8 + (k & 7)] = (_Float16)Wz[idx];
    }
}

// Fused level kernel. 64 rows / 256 threads; 4 row-tiles per B-fragment load.
// LDS: s_hhu (64x392 f16) + 25 KB pool used as x pass-buffer (32 rows) then s_hH (64 rows).
template<bool LEAF>
__global__ __launch_bounds__(256, 2) void level_kernel(
    const float* __restrict__ contents,     // pre-offset, (n,7)
    const int* __restrict__ children,       // pre-offset, (n,2)
    const float* __restrict__ leafContents, // level-9 contents (LEAF only)
    const _Float16* __restrict__ embPrev,   // (!LEAF)
    _Float16* __restrict__ embOut,
    float* __restrict__ finalOut,           // non-null only at level 0
    const float* __restrict__ Wu, const float* __restrict__ bu,
    const _Float16* __restrict__ Pr, const float* __restrict__ br,
    const _Float16* __restrict__ Ph, const float* __restrict__ bh,
    const _Float16* __restrict__ Pz, const float* __restrict__ bz,
    const float* __restrict__ convw, const float* __restrict__ convb)
{
    __shared__ __align__(16) _Float16 s_hhu[ROWS][392];      // 50176 B, [h_L | h_R | u]
    __shared__ __align__(16) char s_pool[32 * 392 * 2];      // 25088 B
    _Float16 (* const s_x)[392]  = (_Float16 (*)[392])s_pool;  // 32-row x pass buffer
    _Float16 (* const s_hH)[136] = (_Float16 (*)[136])s_pool;  // 64-row hH (after passes)

    const int t = threadIdx.x;
    const int row0 = blockIdx.x * ROWS;
    const int col0 = t & 127;
    const int thalf = t >> 7;
    const float cw = convw[0], cb = convb[0];

    float wcol[FEAT];
#pragma unroll
    for (int k = 0; k < FEAT; k++) wcol[k] = Wu[k * H + col0];
    const float bucol = bu[col0];

    // ---- Stage A: u = conv3(c @ Wu + bu) -> s_hhu[:, 256:384]
#pragma unroll 4
    for (int i = 0; i < 32; i++) {
        int r = 2 * i + thalf;
        const float* c = contents + (size_t)(row0 + r) * FEAT;
        float acc = bucol;
#pragma unroll
        for (int k = 0; k < FEAT; k++) acc = fmaf(c[k], wcol[k], acc);
        s_hhu[r][256 + col0] = (_Float16)conv3(acc, cw, cb);
    }

    // ---- Stage B: children embeddings -> s_hhu[:, 0:256]
    if (LEAF) {
#pragma unroll 4
        for (int i = 0; i < 64; i++) {
            int slot = 2 * i + thalf;   // 0..127
            int child = children[row0 * 2 + slot];
            const float* c = leafContents + (size_t)child * FEAT;
            float acc = bucol;
#pragma unroll
            for (int k = 0; k < FEAT; k++) acc = fmaf(c[k], wcol[k], acc);
            s_hhu[slot >> 1][(slot & 1) * 128 + col0] = (_Float16)conv3(acc, cw, cb);
        }
    } else {
        int rp = t >> 4, chunk = t & 15;
#pragma unroll
        for (int p = 0; p < 8; p++) {
            int cr = p * 16 + rp;       // child slot 0..127
            int r = cr >> 1, s = cr & 1;
            int child = children[row0 * 2 + cr];
            uint4 v = *(const uint4*)(embPrev + (size_t)child * H + chunk * 8);
            *(uint4*)&s_hhu[r][s * 128 + chunk * 8] = v;
        }
    }
    __syncthreads();

    const int lane = t & 63;
    const int w = t >> 6;      // wave 0..3
    const int q = lane >> 4;   // 0..3
    const int ln = lane & 15;

    _Float16 xhold[6][2][4];   // x values for rows 32..63, held across stage-D pass 0

    // ---- Stage C: r = sigmoid(hhu @ Wr + br); x = r*hhu  (N=384, K=384, 4 row-tiles)
    {
        const f16x8* PB = (const f16x8*)Pr + (w * 96 + ln);
        f32x4 acc[6][4];
#pragma unroll
        for (int c = 0; c < 6; c++)
#pragma unroll
            for (int rt = 0; rt < 4; rt++) acc[c][rt] = (f32x4){0, 0, 0, 0};
        f16x8 a[4], b[6];
#pragma unroll
        for (int rt = 0; rt < 4; rt++) a[rt] = *(const f16x8*)&s_hhu[rt * 16 + ln][q * 8];
#pragma unroll
        for (int c = 0; c < 6; c++) b[c] = PB[(size_t)q * 384 + c * 16];
#pragma unroll
        for (int kk = 0; kk < 12; kk++) {
            f16x8 ca[4], cb6[6];
#pragma unroll
            for (int rt = 0; rt < 4; rt++) ca[rt] = a[rt];
#pragma unroll
            for (int c = 0; c < 6; c++) cb6[c] = b[c];
            if (kk < 11) {
                int kb = (kk + 1) * 4 + q;
#pragma unroll
                for (int c = 0; c < 6; c++) b[c] = PB[(size_t)kb * 384 + c * 16];
#pragma unroll
                for (int rt = 0; rt < 4; rt++)
                    a[rt] = *(const f16x8*)&s_hhu[rt * 16 + ln][(kk + 1) * 32 + q * 8];
            }
#pragma unroll
            for (int c = 0; c < 6; c++)
#pragma unroll
                for (int rt = 0; rt < 4; rt++)
                    acc[c][rt] = __builtin_amdgcn_mfma_f32_16x16x32_f16(ca[rt], cb6[c], acc[c][rt], 0, 0, 0);
        }
#pragma unroll
        for (int c = 0; c < 6; c++) {
            int colg = w * 96 + c * 16 + ln;
            float bb = br[colg];
#pragma unroll
            for (int rt = 0; rt < 4; rt++)
#pragma unroll
                for (int reg = 0; reg < 4; reg++) {
                    int row = rt * 16 + q * 4 + reg;
                    float rv = sigm(acc[c][rt][reg] + bb);
                    _Float16 xv = (_Float16)(rv * (float)s_hhu[row][colg]);
                    if (rt < 2) s_x[row][colg] = xv;          // rows 0..31 into pass buffer
                    else xhold[c][rt - 2][reg] = xv;          // rows 32..63 held in regs
                }
        }
    }
    __syncthreads();

    // ---- Stage D: h_H = conv3(x @ Wh + bh), two 32-row passes; hH held in regs
    _Float16 hhold[2][2][2][4];  // [pass][cc][rtp][reg]
    const f16x8* PBh = (const f16x8*)Ph + (w * 32 + ln);
#pragma unroll
    for (int pass = 0; pass < 2; pass++) {
        f32x4 accd[2][2];
#pragma unroll
        for (int cc = 0; cc < 2; cc++) { accd[cc][0] = (f32x4){0,0,0,0}; accd[cc][1] = (f32x4){0,0,0,0}; }
        f16x8 a2[2], b2[2];
#pragma unroll
        for (int rtp = 0; rtp < 2; rtp++) a2[rtp] = *(const f16x8*)&s_x[rtp * 16 + ln][q * 8];
#pragma unroll
        for (int cc = 0; cc < 2; cc++) b2[cc] = PBh[(size_t)q * 128 + cc * 16];
#pragma unroll
        for (int kk = 0; kk < 12; kk++) {
            f16x8 ca[2], cb2[2];
            ca[0] = a2[0]; ca[1] = a2[1]; cb2[0] = b2[0]; cb2[1] = b2[1];
            if (kk < 11) {
                int kb = (kk + 1) * 4 + q;
                b2[0] = PBh[(size_t)kb * 128];
                b2[1] = PBh[(size_t)kb * 128 + 16];
                a2[0] = *(const f16x8*)&s_x[ln][(kk + 1) * 32 + q * 8];
                a2[1] = *(const f16x8*)&s_x[16 + ln][(kk + 1) * 32 + q * 8];
            }
#pragma unroll
            for (int cc = 0; cc < 2; cc++) {
                accd[cc][0] = __builtin_amdgcn_mfma_f32_16x16x32_f16(ca[0], cb2[cc], accd[cc][0], 0, 0, 0);
                accd[cc][1] = __builtin_amdgcn_mfma_f32_16x16x32_f16(ca[1], cb2[cc], accd[cc][1], 0, 0, 0);
            }
        }
#pragma unroll
        for (int cc = 0; cc < 2; cc++) {
            float bb = bh[w * 32 + cc * 16 + ln];
#pragma unroll
            for (int rtp = 0; rtp < 2; rtp++)
#pragma unroll
                for (int reg = 0; reg < 4; reg++)
                    hhold[pass][cc][rtp][reg] = (_Float16)conv3(accd[cc][rtp][reg] + bb, cw, cb);
        }
        if (pass == 0) {
            __syncthreads();   // pass-0 x reads complete
            // refill pass buffer with x rows 32..63
#pragma unroll
            for (int c = 0; c < 6; c++) {
                int colg = w * 96 + c * 16 + ln;
#pragma unroll
                for (int rt2 = 0; rt2 < 2; rt2++)
#pragma unroll
                    for (int reg = 0; reg < 4; reg++)
                        s_x[rt2 * 16 + q * 4 + reg][colg] = xhold[c][rt2][reg];
            }
            __syncthreads();
        }
    }
    __syncthreads();   // pass-1 x reads complete; pool is free
    // dump hH registers -> s_hH (64 rows)
#pragma unroll
    for (int pass = 0; pass < 2; pass++)
#pragma unroll
        for (int cc = 0; cc < 2; cc++) {
            int colg = w * 32 + cc * 16 + ln;
#pragma unroll
            for (int rtp = 0; rtp < 2; rtp++)
#pragma unroll
                for (int reg = 0; reg < 4; reg++)
                    s_hH[pass * 32 + rtp * 16 + q * 4 + reg][colg] = hhold[pass][cc][rtp][reg];
        }
    __syncthreads();

    // ---- Stage E: z = [h_H | hhu] @ Wz + bz; softmax gate; write out (N=512, K=512)
    {
        const f16x8* PBz = (const f16x8*)Pz + ln;
#pragma unroll
        for (int sub = 0; sub < 2; sub++) {
            int nc = w * 32 + sub * 16;
            const f16x8* PL = PBz + nc;
            f32x4 acc[4][4];   // [q4][rt]
#pragma unroll
            for (int q4 = 0; q4 < 4; q4++)
#pragma unroll
                for (int rt = 0; rt < 4; rt++) acc[q4][rt] = (f32x4){0, 0, 0, 0};
            f16x8 a[4], b[4];
#pragma unroll
            for (int rt = 0; rt < 4; rt++) a[rt] = *(const f16x8*)&s_hH[rt * 16 + ln][q * 8];
#pragma unroll
            for (int q4 = 0; q4 < 4; q4++) b[q4] = PL[(size_t)q * 512 + q4 * 128];
#pragma unroll
            for (int kk = 0; kk < 16; kk++) {
                f16x8 ca[4], cb4[4];
#pragma unroll
                for (int rt = 0; rt < 4; rt++) ca[rt] = a[rt];
#pragma unroll
                for (int q4 = 0; q4 < 4; q4++) cb4[q4] = b[q4];
                if (kk < 15) {
                    int kb = (kk + 1) * 4 + q;
#pragma unroll
                    for (int q4 = 0; q4 < 4; q4++) b[q4] = PL[(size_t)kb * 512 + q4 * 128];
                    if (kk + 1 < 4) {
#pragma unroll
                        for (int rt = 0; rt < 4; rt++)
                            a[rt] = *(const f16x8*)&s_hH[rt * 16 + ln][(kk + 1) * 32 + q * 8];
                    } else {
                        int k0 = (kk + 1) * 32 - 128;
#pragma unroll
                        for (int rt = 0; rt < 4; rt++)
                            a[rt] = *(const f16x8*)&s_hhu[rt * 16 + ln][k0 + q * 8];
                    }
                }
#pragma unroll
                for (int q4 = 0; q4 < 4; q4++)
#pragma unroll
                    for (int rt = 0; rt < 4; rt++)
                        acc[q4][rt] = __builtin_amdgcn_mfma_f32_16x16x32_f16(ca[rt], cb4[q4], acc[q4][rt], 0, 0, 0);
            }
            int colg = nc + ln;
            float b0 = bz[colg], b1 = bz[128 + colg], b2 = bz[256 + colg], b3 = bz[384 + colg];
#pragma unroll
            for (int rt = 0; rt < 4; rt++)
#pragma unroll
                for (int reg = 0; reg < 4; reg++) {
                    int row = rt * 16 + q * 4 + reg;
                    float z0 = acc[0][rt][reg] + b0;
                    float z1 = acc[1][rt][reg] + b1;
                    float z2 = acc[2][rt][reg] + b2;
                    float z3 = acc[3][rt][reg] + b3;
                    float m = fmaxf(fmaxf(z0, z1), fmaxf(z2, z3));
                    float e0 = __expf(z0 - m), e1 = __expf(z1 - m), e2 = __expf(z2 - m), e3 = __expf(z3 - m);
                    float inv = 1.f / (e0 + e1 + e2 + e3);
                    float hH = (float)s_hH[row][colg];
                    float hL = (float)s_hhu[row][colg];
                    float hR = (float)s_hhu[row][128 + colg];
                    float uu = (float)s_hhu[row][256 + colg];
                    float e = (e0 * hH + e1 * hL + e2 * hR + e3 * uu) * inv;
                    size_t gidx = (size_t)(row0 + row) * H + colg;
                    if (finalOut) finalOut[gidx] = e;
                    else embOut[gidx] = (_Float16)e;
                }
        }
    }
}

extern "C" void kernel_launch(void* const* d_in, const int* in_sizes, int n_in,
                              void* d_out, int out_size, void* d_ws, size_t ws_size,
                              hipStream_t stream) {
    const float* contents = (const float*)d_in[0];
    const int*   children = (const int*)d_in[1];
    const float* Wu = (const float*)d_in[2];
    const float* bu = (const float*)d_in[3];
    const float* Wh = (const float*)d_in[4];
    const float* bh = (const float*)d_in[5];
    const float* Wz = (const float*)d_in[6];
    const float* bz = (const float*)d_in[7];
    const float* Wr = (const float*)d_in[8];
    const float* br = (const float*)d_in[9];
    const float* convw = (const float*)d_in[10];
    const float* convb = (const float*)d_in[11];
    float* out = (float*)d_out;

    // Workspace: [packed weights 1MB][bufA 64MB][bufB 32MB]
    _Float16* Pr = (_Float16*)d_ws;
    _Float16* Ph = Pr + 384 * 384;
    _Float16* Pz = Ph + 384 * 128;
    _Float16* bufA = (_Float16*)((char*)d_ws + (1 << 20));
    _Float16* bufB = bufA + (size_t)262144 * H;

    auto OFFS = [](int j) -> long long { return 1024LL * ((1LL << j) - 1); };

    pack_weights<<<(512 * 512 + 255) / 256, 256, 0, stream>>>(Wr, Wh, Wz, Pr, Ph, Pz);

    // Level 8 with fused leaf (level 9) computation
    {
        int n = 1024 << 8;
        level_kernel<true><<<n / ROWS, 256, 0, stream>>>(
            contents + OFFS(8) * FEAT, children + OFFS(8) * 2,
            contents + OFFS(9) * FEAT, nullptr, bufA, nullptr,
            Wu, bu, Pr, br, Ph, bh, Pz, bz, convw, convb);
    }

    _Float16* prev = bufA;
    _Float16* cur  = bufB;
    for (int j = 7; j >= 0; j--) {
        int n = 1024 << j;
        level_kernel<false><<<n / ROWS, 256, 0, stream>>>(
            contents + OFFS(j) * FEAT, children + OFFS(j) * 2,
            nullptr, prev, cur, (j == 0 ? out : nullptr),
            Wu, bu, Pr, br, Ph, bh, Pz, bz, convw, convb);
        _Float16* tmp = prev; prev = cur; cur = tmp;
    }
}